// Round 1
// baseline (470.351 us; speedup 1.0000x reference)
//
#include <hip/hip_runtime.h>
#include <stdint.h>

#define M_TOK 256
#define N_OUT 16384
#define K_IN  4096
#define BM 128
#define BN 128
#define BK 64
#define NSTEPS (K_IN / BK)   // 64

#define AS1 __attribute__((address_space(1)))
#define AS3 __attribute__((address_space(3)))

typedef short v8s __attribute__((ext_vector_type(8)));
typedef float v16f __attribute__((ext_vector_type(16)));
typedef int   v4i __attribute__((ext_vector_type(4)));
typedef unsigned int uint;

__device__ __forceinline__ unsigned short rne_bf16(float f) {
  uint u = __float_as_uint(f);
  uint r = u + 0x7FFFu + ((u >> 16) & 1u);
  return (unsigned short)(r >> 16);
}
__device__ __forceinline__ float bfbits_to_f(uint h) {
  return __uint_as_float(h << 16);
}

// ---------------- kernel 1: exact dual-bf16 split of x (UNCHANGED) ----------------
__global__ __launch_bounds__(256) void cast_kernel(
    const float* __restrict__ x, unsigned short* __restrict__ xhi,
    unsigned short* __restrict__ xlo) {
  const int i = (blockIdx.x * 256 + threadIdx.x) * 4;
  const float4 f = *(const float4*)(x + i);
  float fs[4] = {f.x, f.y, f.z, f.w};
  unsigned short h[4], l[4];
#pragma unroll
  for (int j = 0; j < 4; ++j) {
    h[j] = rne_bf16(fs[j]);
    l[j] = rne_bf16(fs[j] - bfbits_to_f(h[j]));
  }
  *(ushort4*)(xhi + i) = make_ushort4(h[0], h[1], h[2], h[3]);
  *(ushort4*)(xlo + i) = make_ushort4(l[0], l[1], l[2], l[3]);
}

// ---------------- kernel 2: pipelined dual-bf16 MFMA GEMM ----------------
// BM=128 BN=128 BK=64, grid 256 (1 block/CU), 4 waves of 64x64 via 32x32x16 MFMA.
// LDS double buffer 2 x 48 KiB: per buffer xhi[128][64]bf16 @0, xlo @16384, W @32768.
// Rows are 128 B = 8 chunks of 16 B; chunk c stored at pos c ^ (row&7)  -> every
// aligned 8-lane phase of a ds_read_b128 / ds_write_b128 covers 8 distinct 16B bank
// slots: conflict-free. gload_lds dest is linear (base + lane*16); the swizzle is
// realized by pre-swizzling the per-lane GLOBAL source chunk.
// Pipeline per step (single __syncthreads): issue x-gload_lds(t+1) + W-global(t+1)
// -> MFMA compute(t) -> convert+ds_write W(t+1) -> barrier. W loads have the whole
// compute phase to land; memory stays in flight ~all step.
__global__ __launch_bounds__(256, 1) void gemm_kernel(
    const unsigned short* __restrict__ xhi, const unsigned short* __restrict__ xlo,
    const void* __restrict__ wraw, const float* __restrict__ scales,
    float* __restrict__ out) {
  __shared__ alignas(16) unsigned char smem[98304];
  const int tid = threadIdx.x;
  const int lane = tid & 63;
  const int wid = tid >> 6;

  // --- runtime dtype probe: 64B read, in-bounds under both layouts; uniform result
  const int* wi = (const int*)wraw;
  const signed char* wb = (const signed char*)wraw;
  bool is32 = true;
#pragma unroll
  for (int i = 0; i < 16; ++i) {
    const int v = wi[i];
    is32 = is32 && (v >= -128) && (v <= 127);
  }

  // XCD swizzle: the mb-pair (only 2 readers of each W strip) lands on one XCD,
  // and each XCD works a contiguous nb range (W streamed past L2 exactly once).
  const int bid = blockIdx.x;
  const int logical = (bid & 7) * 32 + (bid >> 3);  // bijective for 256 blocks
  const int mb = logical & 1;
  const int nb = logical >> 1;
  const int m0 = mb * BM;
  const int n0 = nb * BN;

  // --- x staging descriptors: per wave 4 gload_lds per plane (8 rows each)
  const int l8 = lane >> 3, e7 = lane & 7;
  const int cx = e7 ^ l8;  // fetch the global chunk that belongs at LDS pos lane&7
  size_t xoff[4];
  uint xdst[4];
#pragma unroll
  for (int j = 0; j < 4; ++j) {
    const int rw = wid * 4 + j;                       // 0..15
    xoff[j] = (size_t)(m0 + rw * 8 + l8) * K_IN + (size_t)(cx * 8);
    xdst[j] = (uint)(rw * 1024);
  }

  // --- W staging descriptors: thread t owns row t>>1, k-half t&1 (32 values)
  const int wrow = tid >> 1, wh = tid & 1;
  const int* w32base = wi + (size_t)(n0 + wrow) * K_IN + wh * 32;
  const signed char* w8base = wb + (size_t)(n0 + wrow) * K_IN + wh * 32;
  uint wpos[4];
#pragma unroll
  for (int cc = 0; cc < 4; ++cc)
    wpos[cc] = 32768u + (uint)(wrow * 128) + (uint)((((4 * wh + cc) ^ (wrow & 7))) << 4);

  // --- compute descriptors (32x32x16: A row=l&31, k=(l>>5)*8; C col=l&31,
  //     row=(reg&3)+8*(reg>>2)+4*(l>>5); verified layouts)
  const int l31 = lane & 31, hi5 = lane >> 5;
  const int wm = (wid & 1) * 64, wn = (wid >> 1) * 64;
  uint arow[2], brow[2];
#pragma unroll
  for (int f = 0; f < 2; ++f) {
    arow[f] = (uint)((wm + f * 32 + l31) * 128);
    brow[f] = 32768u + (uint)((wn + f * 32 + l31) * 128);
  }

  v16f acc[2][2] = {};
  v4i wt[8];  // W stage regs: 8 x dwordx4 (int32 path) or 2 (int8 path)

  auto stage_tile = [&](int s, uint bo) {
#pragma unroll
    for (int j = 0; j < 4; ++j) {
      __builtin_amdgcn_global_load_lds(
          (const AS1 void*)(xhi + xoff[j] + (size_t)s * BK),
          (AS3 void*)(smem + bo + xdst[j]), 16, 0, 0);
      __builtin_amdgcn_global_load_lds(
          (const AS1 void*)(xlo + xoff[j] + (size_t)s * BK),
          (AS3 void*)(smem + bo + 16384 + xdst[j]), 16, 0, 0);
    }
    if (is32) {
#pragma unroll
      for (int i = 0; i < 8; ++i)
        wt[i] = *(const v4i*)(w32base + (size_t)s * BK + i * 4);
    } else {
      wt[0] = *(const v4i*)(w8base + (size_t)s * BK);
      wt[1] = *(const v4i*)(w8base + (size_t)s * BK + 16);
    }
  };

  auto conv_write_w = [&](uint bo) {
    int e[32];
    if (is32) {
#pragma unroll
      for (int i = 0; i < 8; ++i) {
        e[4 * i + 0] = wt[i].x; e[4 * i + 1] = wt[i].y;
        e[4 * i + 2] = wt[i].z; e[4 * i + 3] = wt[i].w;
      }
    } else {
      const signed char* bs = (const signed char*)wt;
#pragma unroll
      for (int j = 0; j < 32; ++j) e[j] = (int)bs[j];
    }
    uint d[16];
#pragma unroll
    for (int j = 0; j < 16; ++j)  // ints |v|<=128 are exact in bf16: truncate
      d[j] = (__float_as_uint((float)e[2 * j]) >> 16) |
             (__float_as_uint((float)e[2 * j + 1]) & 0xffff0000u);
#pragma unroll
    for (int cc = 0; cc < 4; ++cc) {
      v4i wv;
      wv.x = (int)d[4 * cc + 0]; wv.y = (int)d[4 * cc + 1];
      wv.z = (int)d[4 * cc + 2]; wv.w = (int)d[4 * cc + 3];
      *(v4i*)(smem + bo + wpos[cc]) = wv;
    }
  };

  // prologue: stage step 0 into buffer 0
  stage_tile(0, 0u);
  conv_write_w(0u);  // compiler inserts the vmcnt wait on wt use
  __syncthreads();

  for (int t = 0; t < NSTEPS; ++t) {
    const uint bc = (t & 1) ? 49152u : 0u;
    const uint bn_ = bc ^ 49152u;
    const bool stagenext = (t + 1 < NSTEPS);
    if (stagenext) stage_tile(t + 1, bn_);
    __builtin_amdgcn_sched_barrier(0);  // pin prefetch issue above compute

#pragma unroll
    for (int kc = 0; kc < 4; ++kc) {
      const uint pos = (uint)(((kc * 2 + hi5) ^ e7) << 4);
      v8s ah[2], al[2], b[2];
#pragma unroll
      for (int f = 0; f < 2; ++f) {
        ah[f] = *(const v8s*)(smem + bc + arow[f] + pos);
        al[f] = *(const v8s*)(smem + bc + 16384u + arow[f] + pos);
        b[f]  = *(const v8s*)(smem + bc + brow[f] + pos);
      }
#pragma unroll
      for (int mf = 0; mf < 2; ++mf)
#pragma unroll
        for (int nf = 0; nf < 2; ++nf) {
          acc[mf][nf] = __builtin_amdgcn_mfma_f32_32x32x16_bf16(ah[mf], b[nf], acc[mf][nf], 0, 0, 0);
          acc[mf][nf] = __builtin_amdgcn_mfma_f32_32x32x16_bf16(al[mf], b[nf], acc[mf][nf], 0, 0, 0);
        }
    }

    if (stagenext) conv_write_w(bn_);  // W(t+1) loads landed during compute
    __syncthreads();                   // publish buf^1; protect buf cur
  }

  // epilogue: 32x32 C/D layout: col = lane&31, row = (reg&3) + 8*(reg>>2) + 4*(lane>>5)
#pragma unroll
  for (int nf = 0; nf < 2; ++nf) {
    const int n = n0 + wn + nf * 32 + l31;
    const float scl = scales[n];
#pragma unroll
    for (int mf = 0; mf < 2; ++mf)
#pragma unroll
      for (int reg = 0; reg < 16; ++reg) {
        const int m = m0 + wm + mf * 32 + (reg & 3) + 8 * (reg >> 2) + 4 * hi5;
        out[(size_t)m * N_OUT + n] = acc[mf][nf][reg] * scl;
      }
  }
}

// ---------------- fallback (workspace too small); also dtype-probed ----------------
__global__ void naive_kernel(const float* __restrict__ x, const void* __restrict__ wraw,
                             const float* __restrict__ scales, float* __restrict__ out) {
  const int* wi = (const int*)wraw;
  bool is32 = true;
  for (int i = 0; i < 16; ++i) { int v = wi[i]; is32 = is32 && v >= -128 && v <= 127; }
  const int idx = blockIdx.x * 256 + threadIdx.x;
  const int m = idx >> 14;
  const int n = idx & (N_OUT - 1);
  const float* xr = x + (size_t)m * K_IN;
  float acc = 0.f;
  if (is32) {
    const int* wr = wi + (size_t)n * K_IN;
    for (int k = 0; k < K_IN; ++k) acc += xr[k] * (float)wr[k];
  } else {
    const signed char* wr = (const signed char*)wraw + (size_t)n * K_IN;
    for (int k = 0; k < K_IN; ++k) acc += xr[k] * (float)wr[k];
  }
  out[idx] = acc * scales[n];
}

extern "C" void kernel_launch(void* const* d_in, const int* in_sizes, int n_in,
                              void* d_out, int out_size, void* d_ws, size_t ws_size,
                              hipStream_t stream) {
  const float* x = (const float*)d_in[0];
  const void* w = d_in[1];  // dtype resolved on-device (int8 vs int32 materialization)
  const float* scales = (const float*)d_in[2];
  float* out = (float*)d_out;
  if (ws_size >= (size_t)4 * 1024 * 1024) {
    unsigned short* xhi = (unsigned short*)d_ws;
    unsigned short* xlo = xhi + (size_t)M_TOK * K_IN;
    cast_kernel<<<(M_TOK * K_IN) / 1024, 256, 0, stream>>>(x, xhi, xlo);
    gemm_kernel<<<256, 256, 0, stream>>>(xhi, xlo, w, scales, out);
  } else {
    naive_kernel<<<(M_TOK * N_OUT) / 256, 256, 0, stream>>>(x, w, scales, out);
  }
}